// Round 1
// baseline (357.902 us; speedup 1.0000x reference)
//
#include <hip/hip_runtime.h>
#include <math.h>

// Problem constants (match reference)
#define MB 8      // batch
#define MM 384    // checks
#define NN 1536   // variables
#define LL 20     // layers
#define RW 8      // row weight of H
#define NE (MM*RW)  // 3072 edges

// ---------------------------------------------------------------------------
// Kernel A: extract the RW column indices of each row of H.
// One block (one wave, 64 lanes) per row; ballot-compaction preserves order.
// ---------------------------------------------------------------------------
__global__ void extract_cols_kernel(const float* __restrict__ H,
                                    int* __restrict__ col_idx) {
    int m = blockIdx.x;
    int lane = threadIdx.x;  // 0..63
    const float* row = H + (size_t)m * NN;
    int count = 0;
    for (int base = 0; base < NN; base += 64) {
        float v = row[base + lane];
        unsigned long long mask = __ballot(v != 0.0f);
        if (v != 0.0f) {
            int pos = count + (int)__popcll(mask & ((1ull << lane) - 1ull));
            if (pos < RW) col_idx[m * RW + pos] = base + lane;
        }
        count += (int)__popcll(mask);
    }
}

// ---------------------------------------------------------------------------
// Kernel B: gather per-edge weights once so the BP loop reads contiguous data.
//   base_e[l][e] = llrs[c] * w_llr[l][c]
//   wde_e [l][e] = w_de[l][m][c]
//   marg_e[e]    = marg_de[m][c]
// ---------------------------------------------------------------------------
__global__ void gather_weights_kernel(const int* __restrict__ col_idx,
                                      const float* __restrict__ llrs,
                                      const float* __restrict__ w_llr,
                                      const float* __restrict__ w_de,
                                      const float* __restrict__ marg_de,
                                      float* __restrict__ base_e,
                                      float* __restrict__ wde_e,
                                      float* __restrict__ marg_e) {
    int idx = blockIdx.x * blockDim.x + threadIdx.x;
    if (idx < NE) {
        int m = idx / RW;
        int c = col_idx[idx];
        marg_e[idx] = marg_de[m * NN + c];
    }
    if (idx < LL * NE) {
        int l = idx / NE;
        int e = idx - l * NE;
        int m = e / RW;
        int c = col_idx[e];
        base_e[idx] = llrs[c] * w_llr[l * NN + c];
        wde_e[idx]  = w_de[(size_t)l * MM * NN + (size_t)m * NN + c];
    }
}

// ---------------------------------------------------------------------------
// Main BP kernel: one block per batch element, 384 threads (1 thread = 1 check
// row). All per-batch state lives in LDS; 20-layer loop with 4 barriers/layer.
// ---------------------------------------------------------------------------
__global__ __launch_bounds__(384) void bp_kernel(
    const float* __restrict__ synd,       // (B,M,1)
    const float* __restrict__ errors,     // (B,N)
    const float* __restrict__ llrs,       // (N)
    const float* __restrict__ marg_llr,   // (N)
    const float* __restrict__ res_w,      // (L)
    const float* __restrict__ rhos,       // (L)
    const int*   __restrict__ col_idx,    // (E)
    const float* __restrict__ marg_e_g,   // (E)
    const float* __restrict__ base_e_g,   // (L,E)
    const float* __restrict__ wde_e_g,    // (L,E)
    float* __restrict__ out) {

    __shared__ float s_msg[NE];
    __shared__ float s_S[NN];
    __shared__ float s_bel[NN];
    __shared__ float s_marg[NE];
    __shared__ float s_sign[MM];
    __shared__ int   s_col[NE];
    __shared__ float s_red[6];

    const int b = blockIdx.x;
    const int t = threadIdx.x;  // 0..383; also the check-row index

    // One-time init
    for (int e = t; e < NE; e += 384) {
        s_msg[e]  = 0.0f;
        s_marg[e] = marg_e_g[e];
        s_col[e]  = col_idx[e];
    }
    s_sign[t] = 1.0f - 2.0f * synd[b * MM + t];

    // Cache per-thread belief bias and error terms (N/384 = 4 per thread)
    float bel_bias[4];
    float omeg[4];  // 1 - errors
    #pragma unroll
    for (int i = 0; i < 4; ++i) {
        int n = t + i * 384;
        bel_bias[i] = llrs[n] * marg_llr[n];
        omeg[i]     = 1.0f - errors[b * NN + n];
    }
    __syncthreads();

    float loss = 0.0f;

    for (int l = 0; l < LL; ++l) {
        const float* base_e = base_e_g + l * NE;
        const float* wde_e  = wde_e_g + l * NE;
        const float rw  = res_w[l];
        const float rho = rhos[l];

        // Phase 1: reset S and beliefs
        #pragma unroll
        for (int i = 0; i < 4; ++i) {
            int n = t + i * 384;
            s_S[n]   = 0.0f;
            s_bel[n] = bel_bias[i];
        }
        __syncthreads();

        // Phase 2: variable-node sum S[n] = sum_edges msg * w_de (scatter)
        {
            const int m = t;
            #pragma unroll
            for (int k = 0; k < RW; ++k) {
                int e = m * RW + k;
                atomicAdd(&s_S[s_col[e]], s_msg[e] * wde_e[e]);
            }
        }
        __syncthreads();

        // Phase 3: check-node update (tanh-product with self-exclusion by division)
        {
            const int m = t;
            const float sgn = s_sign[m];
            float d[RW];
            float p = 1.0f;
            #pragma unroll
            for (int k = 0; k < RW; ++k) {
                int e = m * RW + k;
                float te = base_e[e] + s_S[s_col[e]] - s_msg[e];
                float dd = tanhf(0.5f * te);
                if (dd == 0.0f) dd = 1.0f;  // matches jnp.where(d==0,1,d)
                d[k] = dd;
                p *= dd;
            }
            #pragma unroll
            for (int k = 0; k < RW; ++k) {
                int e = m * RW + k;
                float x  = p / d[k];
                float nm = 2.0f * atanhf(x) * sgn + rw * s_msg[e];
                s_msg[e] = nm;
                atomicAdd(&s_bel[s_col[e]], nm * s_marg[e]);
            }
        }
        __syncthreads();

        // Phase 4: loss = sum_n softplus(bel) - (1-e)*bel, weighted by rho
        float acc = 0.0f;
        #pragma unroll
        for (int i = 0; i < 4; ++i) {
            int n = t + i * 384;
            float bel = s_bel[n];
            float sp  = fmaxf(bel, 0.0f) + log1pf(expf(-fabsf(bel)));
            acc += sp - omeg[i] * bel;
        }
        loss += rho * acc;
        __syncthreads();  // protect s_bel/s_S before next layer's reset
    }

    // Block-wide reduction of loss
    #pragma unroll
    for (int off = 32; off > 0; off >>= 1)
        loss += __shfl_down(loss, off, 64);
    int wave = t >> 6, lane = t & 63;
    if (lane == 0) s_red[wave] = loss;
    __syncthreads();
    if (t == 0) {
        float tot = 0.0f;
        #pragma unroll
        for (int w = 0; w < 6; ++w) tot += s_red[w];
        atomicAdd(out, tot * (1.0f / (float)MB));
    }
}

// ---------------------------------------------------------------------------
extern "C" void kernel_launch(void* const* d_in, const int* in_sizes, int n_in,
                              void* d_out, int out_size, void* d_ws, size_t ws_size,
                              hipStream_t stream) {
    const float* synd     = (const float*)d_in[0];  // (B,M,1)
    const float* errors   = (const float*)d_in[1];  // (B,N)
    const float* H        = (const float*)d_in[2];  // (M,N)
    const float* llrs     = (const float*)d_in[3];  // (N)
    const float* w_de     = (const float*)d_in[4];  // (L,M,N)
    const float* w_llr    = (const float*)d_in[5];  // (L,N)
    const float* marg_de  = (const float*)d_in[6];  // (M,N)
    const float* marg_llr = (const float*)d_in[7];  // (N)
    const float* res_w    = (const float*)d_in[8];  // (L)
    const float* rhos     = (const float*)d_in[9];  // (L)
    float* out = (float*)d_out;

    // Workspace layout (4-byte elements)
    int*   col_idx = (int*)d_ws;            // NE ints
    float* marg_e  = (float*)d_ws + NE;     // NE floats
    float* base_e  = marg_e + NE;           // L*NE floats
    float* wde_e   = base_e + LL * NE;      // L*NE floats

    // d_out is re-poisoned to 0xAA before every timed launch — zero it.
    hipMemsetAsync(d_out, 0, sizeof(float), stream);

    extract_cols_kernel<<<MM, 64, 0, stream>>>(H, col_idx);
    gather_weights_kernel<<<(LL * NE + 255) / 256, 256, 0, stream>>>(
        col_idx, llrs, w_llr, w_de, marg_de, base_e, wde_e, marg_e);
    bp_kernel<<<MB, 384, 0, stream>>>(synd, errors, llrs, marg_llr, res_w, rhos,
                                      col_idx, marg_e, base_e, wde_e, out);
}

// Round 2
// 288.232 us; speedup vs baseline: 1.2417x; 1.2417x over previous
//
#include <hip/hip_runtime.h>
#include <math.h>

// Problem constants (match reference)
#define MB 8      // batch
#define MM 384    // checks
#define NN 1536   // variables
#define LL 20     // layers
#define RW 8      // row weight of H
#define NE (MM*RW)  // 3072 edges

// ---------------------------------------------------------------------------
// Fused setup: one block (one wave) per check row.
//  1) ballot-compact the RW column indices of H row m
//  2) gather per-edge weights for all 20 layers into contiguous ws arrays
//  3) block 0 zeroes the output scalar
// ---------------------------------------------------------------------------
__global__ __launch_bounds__(64) void setup_kernel(
    const float* __restrict__ H,
    const float* __restrict__ llrs,
    const float* __restrict__ w_llr,
    const float* __restrict__ w_de,
    const float* __restrict__ marg_de,
    int*   __restrict__ col_idx,
    float* __restrict__ marg_e,
    float* __restrict__ base_e,
    float* __restrict__ wde_e,
    float* __restrict__ out) {
    const int m = blockIdx.x;
    const int lane = threadIdx.x;  // 0..63
    __shared__ int s_col[RW];

    const float* row = H + (size_t)m * NN;
    int count = 0;
    for (int base = 0; base < NN; base += 64) {
        float v = row[base + lane];
        unsigned long long mask = __ballot(v != 0.0f);
        if (v != 0.0f) {
            int pos = count + (int)__popcll(mask & ((1ull << lane) - 1ull));
            if (pos < RW) s_col[pos] = base + lane;
        }
        count += (int)__popcll(mask);
    }
    __syncthreads();

    if (lane < RW) {
        int c = s_col[lane];
        col_idx[m * RW + lane] = c;
        marg_e[m * RW + lane]  = marg_de[m * NN + c];
    }
    if (m == 0 && lane == 0) out[0] = 0.0f;

    // 20 layers x 8 edges = 160 gathers per row, 64 threads
    for (int idx = lane; idx < LL * RW; idx += 64) {
        int l = idx >> 3;
        int k = idx & 7;
        int c = s_col[k];
        base_e[l * NE + m * RW + k] = llrs[c] * w_llr[l * NN + c];
        wde_e [l * NE + m * RW + k] = w_de[(size_t)l * MM * NN + (size_t)m * NN + c];
    }
}

// ---------------------------------------------------------------------------
// Main BP kernel: one block per batch element, 384 threads = 1 thread per
// check row. msg / cols / marg / weights live in REGISTERS; only the
// cross-thread exchange arrays (S, beliefs) live in LDS. 3 barriers/layer.
// Fast math: tanh(t/2) = 1 - 2*rcp(e^t+1); self-exclusion via prefix/suffix
// products (no divides); 2*atanh(x) = log((1+x)*rcp(1-x)).
// ---------------------------------------------------------------------------
__global__ __launch_bounds__(384) void bp_kernel(
    const float* __restrict__ synd,       // (B,M,1)
    const float* __restrict__ errors,     // (B,N)
    const float* __restrict__ llrs,       // (N)
    const float* __restrict__ marg_llr,   // (N)
    const float* __restrict__ res_w,      // (L)
    const float* __restrict__ rhos,       // (L)
    const int*   __restrict__ col_idx,    // (E)
    const float* __restrict__ marg_e_g,   // (E)
    const float* __restrict__ base_e_g,   // (L,E)
    const float* __restrict__ wde_e_g,    // (L,E)
    float* __restrict__ out) {

    __shared__ float s_S[NN];
    __shared__ float s_bel[NN];
    __shared__ float s_red[6];

    const int b = blockIdx.x;
    const int t = threadIdx.x;  // check-row index

    // ---- per-thread register state ----
    int   col[RW];
    float marg[RW];
    float msg[RW];
    {
        const int4* ci = (const int4*)(col_idx + t * RW);
        ((int4*)col)[0] = ci[0]; ((int4*)col)[1] = ci[1];
        const float4* mg = (const float4*)(marg_e_g + t * RW);
        ((float4*)marg)[0] = mg[0]; ((float4*)marg)[1] = mg[1];
    }
    #pragma unroll
    for (int k = 0; k < RW; ++k) msg[k] = 0.0f;

    const float sgn = 1.0f - 2.0f * synd[b * MM + t];

    float bias[4], omeg[4];
    #pragma unroll
    for (int i = 0; i < 4; ++i) {
        int n = t + i * 384;
        bias[i] = llrs[n] * marg_llr[n];
        omeg[i] = 1.0f - errors[b * NN + n];
        s_S[n]   = 0.0f;
        s_bel[n] = bias[i];
    }

    // ---- prefetch layer 0 weights into registers ----
    float bc[RW], wc[RW], bn[RW], wn[RW];
    {
        const float4* bp4 = (const float4*)(base_e_g + t * RW);
        ((float4*)bc)[0] = bp4[0]; ((float4*)bc)[1] = bp4[1];
        const float4* wp4 = (const float4*)(wde_e_g + t * RW);
        ((float4*)wc)[0] = wp4[0]; ((float4*)wc)[1] = wp4[1];
    }

    float loss = 0.0f;
    __syncthreads();

    for (int l = 0; l < LL; ++l) {
        // prefetch next layer's weights (hidden behind this layer's compute)
        {
            int lp = (l + 1 < LL) ? (l + 1) : l;
            const float4* bp4 = (const float4*)(base_e_g + lp * NE + t * RW);
            ((float4*)bn)[0] = bp4[0]; ((float4*)bn)[1] = bp4[1];
            const float4* wp4 = (const float4*)(wde_e_g + lp * NE + t * RW);
            ((float4*)wn)[0] = wp4[0]; ((float4*)wn)[1] = wp4[1];
        }
        const float rw_  = res_w[l];
        const float rho  = rhos[l];

        // Phase 2: variable-node sums S[n] += msg * w_de (scatter)
        #pragma unroll
        for (int k = 0; k < RW; ++k)
            atomicAdd(&s_S[col[k]], msg[k] * wc[k]);
        __syncthreads();

        // Phase 3: check-node update
        float d[RW];
        #pragma unroll
        for (int k = 0; k < RW; ++k) {
            float te = bc[k] + s_S[col[k]] - msg[k];
            float e  = __expf(te);                         // v_exp_f32
            float dd = 1.0f - 2.0f * __builtin_amdgcn_rcpf(e + 1.0f);
            dd = fminf(fmaxf(dd, -1.0f), 1.0f);            // guard rcp rounding
            if (dd == 0.0f) dd = 1.0f;                     // jnp.where(d==0,1,d)
            d[k] = dd;
        }
        // exclusive products via prefix/suffix (no divides)
        float pre[RW], suf[RW];
        pre[0] = 1.0f;
        #pragma unroll
        for (int k = 1; k < RW; ++k) pre[k] = pre[k-1] * d[k-1];
        suf[RW-1] = 1.0f;
        #pragma unroll
        for (int k = RW-2; k >= 0; --k) suf[k] = suf[k+1] * d[k+1];

        #pragma unroll
        for (int k = 0; k < RW; ++k) {
            float x  = pre[k] * suf[k];
            float r  = (1.0f + x) * __builtin_amdgcn_rcpf(1.0f - x);
            float nm = sgn * __logf(r) + rw_ * msg[k];     // 2*atanh(x)*sgn + res*msg
            msg[k] = nm;
            atomicAdd(&s_bel[col[k]], nm * marg[k]);
        }
        __syncthreads();

        // Phase 4: loss over beliefs; reset S/bel for next layer (owned slots)
        float acc = 0.0f;
        #pragma unroll
        for (int i = 0; i < 4; ++i) {
            int n = t + i * 384;
            float be = s_bel[n];
            float sp = fmaxf(be, 0.0f) + __logf(1.0f + __expf(-fabsf(be)));
            acc += sp - omeg[i] * be;
            s_bel[n] = bias[i];
            s_S[n]   = 0.0f;
        }
        loss += rho * acc;

        // rotate prefetched weights into current
        #pragma unroll
        for (int k = 0; k < RW; ++k) { bc[k] = bn[k]; wc[k] = wn[k]; }
        __syncthreads();   // protect resets vs next layer's scatters
    }

    // ---- block-wide loss reduction ----
    #pragma unroll
    for (int off = 32; off > 0; off >>= 1)
        loss += __shfl_down(loss, off, 64);
    int wave = t >> 6, lane = t & 63;
    if (lane == 0) s_red[wave] = loss;
    __syncthreads();
    if (t == 0) {
        float tot = 0.0f;
        #pragma unroll
        for (int w = 0; w < 6; ++w) tot += s_red[w];
        atomicAdd(out, tot * (1.0f / (float)MB));
    }
}

// ---------------------------------------------------------------------------
extern "C" void kernel_launch(void* const* d_in, const int* in_sizes, int n_in,
                              void* d_out, int out_size, void* d_ws, size_t ws_size,
                              hipStream_t stream) {
    const float* synd     = (const float*)d_in[0];  // (B,M,1)
    const float* errors   = (const float*)d_in[1];  // (B,N)
    const float* H        = (const float*)d_in[2];  // (M,N)
    const float* llrs     = (const float*)d_in[3];  // (N)
    const float* w_de     = (const float*)d_in[4];  // (L,M,N)
    const float* w_llr    = (const float*)d_in[5];  // (L,N)
    const float* marg_de  = (const float*)d_in[6];  // (M,N)
    const float* marg_llr = (const float*)d_in[7];  // (N)
    const float* res_w    = (const float*)d_in[8];  // (L)
    const float* rhos     = (const float*)d_in[9];  // (L)
    float* out = (float*)d_out;

    // Workspace layout (4-byte elements, all 16B-aligned partitions)
    int*   col_idx = (int*)d_ws;            // NE ints
    float* marg_e  = (float*)d_ws + NE;     // NE floats
    float* base_e  = marg_e + NE;           // L*NE floats
    float* wde_e   = base_e + LL * NE;      // L*NE floats

    setup_kernel<<<MM, 64, 0, stream>>>(H, llrs, w_llr, w_de, marg_de,
                                        col_idx, marg_e, base_e, wde_e, out);
    bp_kernel<<<MB, 384, 0, stream>>>(synd, errors, llrs, marg_llr, res_w, rhos,
                                      col_idx, marg_e, base_e, wde_e, out);
}

// Round 3
// 272.737 us; speedup vs baseline: 1.3123x; 1.0568x over previous
//
#include <hip/hip_runtime.h>
#include <math.h>

// Problem constants (match reference)
#define MB 8      // batch
#define MM 384    // checks
#define NN 1536   // variables
#define LL 20     // layers
#define RW 8      // row weight of H
#define NE (MM*RW)  // 3072 edges

// ---------------------------------------------------------------------------
// Fused setup: one block (256 thr = 4 waves) per check row.
//  Each wave ballot-scans a quarter of H row m (6 chunks instead of 24),
//  quarters are merged in order, then 256 threads gather all per-layer
//  edge weights. Block 0 zeroes the output scalar.
// ---------------------------------------------------------------------------
__global__ __launch_bounds__(256) void setup_kernel(
    const float* __restrict__ H,
    const float* __restrict__ llrs,
    const float* __restrict__ w_llr,
    const float* __restrict__ w_de,
    const float* __restrict__ marg_de,
    int*   __restrict__ col_idx,
    float* __restrict__ marg_e,
    float* __restrict__ base_e,
    float* __restrict__ wde_e,
    float* __restrict__ out) {
    const int m = blockIdx.x;
    const int t = threadIdx.x;
    const int w = t >> 6, lane = t & 63;
    __shared__ int s_qcol[4][RW];
    __shared__ int s_qcnt[4];
    __shared__ int s_col[RW];

    const float* row = H + (size_t)m * NN;
    int count = 0;
    // wave w scans columns [w*384, (w+1)*384)
    for (int c0 = w * 384; c0 < (w + 1) * 384; c0 += 64) {
        float v = row[c0 + lane];
        unsigned long long mask = __ballot(v != 0.0f);
        if (v != 0.0f) {
            int pos = count + (int)__popcll(mask & ((1ull << lane) - 1ull));
            if (pos < RW) s_qcol[w][pos] = c0 + lane;
        }
        count += (int)__popcll(mask);
    }
    if (lane == 0) s_qcnt[w] = (count < RW) ? count : RW;
    __syncthreads();
    if (t == 0) {
        int off = 0;
        for (int q = 0; q < 4; ++q)
            for (int i = 0; i < s_qcnt[q]; ++i) {
                if (off < RW) s_col[off] = s_qcol[q][i];
                ++off;
            }
    }
    __syncthreads();

    if (t < RW) {
        int c = s_col[t];
        col_idx[m * RW + t] = c;
        marg_e[m * RW + t]  = marg_de[m * NN + c];
    }
    if (m == 0 && t == 0) out[0] = 0.0f;

    // 20 layers x 8 edges = 160 gathers per row; 256 threads -> 1 each
    for (int idx = t; idx < LL * RW; idx += 256) {
        int l = idx >> 3;
        int k = idx & 7;
        int c = s_col[k];
        base_e[l * NE + m * RW + k] = llrs[c] * w_llr[l * NN + c];
        wde_e [l * NE + m * RW + k] = w_de[(size_t)l * MM * NN + (size_t)m * NN + c];
    }
}

// ---------------------------------------------------------------------------
// Main BP kernel: one block per batch element, 384 threads = 1 thread per
// check row. ONE barrier per layer:
//   - S uses a 3-buffer rotation: read S[l%3], scatter S[(l+1)%3] (fused into
//     the check-node loop using NEXT layer's w_de; w_de[0] is never needed
//     since msg_0 = 0), reset idle S[(l+2)%3].
//   - beliefs ping-pong over 2 buffers; layer l-1's loss is computed at the
//     top of layer l (deferred read-out — feeds nothing downstream).
//   - res_w / rhos staged in LDS pre-loop; per-edge weights prefetched into
//     registers one layer ahead.
// ---------------------------------------------------------------------------
__global__ __launch_bounds__(384) void bp_kernel(
    const float* __restrict__ synd,       // (B,M,1)
    const float* __restrict__ errors,     // (B,N)
    const float* __restrict__ llrs,       // (N)
    const float* __restrict__ marg_llr,   // (N)
    const float* __restrict__ res_w,      // (L)
    const float* __restrict__ rhos,       // (L)
    const int*   __restrict__ col_idx,    // (E)
    const float* __restrict__ marg_e_g,   // (E)
    const float* __restrict__ base_e_g,   // (L,E)
    const float* __restrict__ wde_e_g,    // (L,E)
    float* __restrict__ out) {

    __shared__ float s_S[3][NN];
    __shared__ float s_bel[2][NN];
    __shared__ float s_rw[LL];
    __shared__ float s_rho[LL];
    __shared__ float s_red[6];

    const int b = blockIdx.x;
    const int t = threadIdx.x;  // check-row index

    // ---- per-thread register state ----
    int   col[RW];
    float marg[RW];
    float msg[RW];
    {
        const int4* ci = (const int4*)(col_idx + t * RW);
        ((int4*)col)[0] = ci[0]; ((int4*)col)[1] = ci[1];
        const float4* mg = (const float4*)(marg_e_g + t * RW);
        ((float4*)marg)[0] = mg[0]; ((float4*)marg)[1] = mg[1];
    }
    #pragma unroll
    for (int k = 0; k < RW; ++k) msg[k] = 0.0f;

    const float sgn = 1.0f - 2.0f * synd[b * MM + t];

    float bias[4], omeg[4];
    #pragma unroll
    for (int i = 0; i < 4; ++i) {
        int n = t + i * 384;
        bias[i] = llrs[n] * marg_llr[n];
        omeg[i] = 1.0f - errors[b * NN + n];
        s_S[0][n] = 0.0f; s_S[1][n] = 0.0f; s_S[2][n] = 0.0f;
        s_bel[0][n] = bias[i]; s_bel[1][n] = bias[i];
    }
    if (t < LL) { s_rw[t] = res_w[t]; s_rho[t] = rhos[t]; }

    // ---- prefetch: bc = base_e[layer 0], wS = wde_e[layer 1] ----
    float bc[RW], wS[RW], bn[RW], wn2[RW];
    {
        const float4* bp4 = (const float4*)(base_e_g + t * RW);
        ((float4*)bc)[0] = bp4[0]; ((float4*)bc)[1] = bp4[1];
        const float4* wp4 = (const float4*)(wde_e_g + 1 * NE + t * RW);
        ((float4*)wS)[0] = wp4[0]; ((float4*)wS)[1] = wp4[1];
    }

    float loss = 0.0f;
    __syncthreads();

    for (int l = 0; l < LL; ++l) {
        // prefetch base_e[l+1] and wde_e[l+2] (consumed next layer)
        {
            int lb = (l + 1 < LL) ? (l + 1) : (LL - 1);
            int lw = (l + 2 < LL) ? (l + 2) : (LL - 1);
            const float4* bp4 = (const float4*)(base_e_g + lb * NE + t * RW);
            ((float4*)bn)[0]  = bp4[0]; ((float4*)bn)[1]  = bp4[1];
            const float4* wp4 = (const float4*)(wde_e_g + lw * NE + t * RW);
            ((float4*)wn2)[0] = wp4[0]; ((float4*)wn2)[1] = wp4[1];
        }

        // deferred loss for layer l-1 (independent of this layer's chain)
        if (l > 0) {
            const float rr = s_rho[l - 1];
            const int   pb = (l - 1) & 1;
            float acc = 0.0f;
            #pragma unroll
            for (int i = 0; i < 4; ++i) {
                int n = t + i * 384;
                float be = s_bel[pb][n];
                float sp = fmaxf(be, 0.0f) + __logf(1.0f + __expf(-fabsf(be)));
                acc += sp - omeg[i] * be;
                s_bel[pb][n] = bias[i];   // reset for reuse at layer l+1
            }
            loss += rr * acc;
        }

        // reset the idle S buffer (owned slots; consumed two layers ago)
        {
            const int sb = (l + 2) % 3;
            #pragma unroll
            for (int i = 0; i < 4; ++i) s_S[sb][t + i * 384] = 0.0f;
        }

        // check-node update: gather S[l%3], compute msgs, scatter S[(l+1)%3]
        const float rw_ = s_rw[l];
        const int cs = l % 3, ns = (l + 1) % 3, bb = l & 1;

        float d[RW];
        #pragma unroll
        for (int k = 0; k < RW; ++k) {
            float te = bc[k] + s_S[cs][col[k]] - msg[k];
            float e  = __expf(te);                          // v_exp_f32
            float dd = 1.0f - 2.0f * __builtin_amdgcn_rcpf(e + 1.0f);
            dd = fminf(fmaxf(dd, -1.0f), 1.0f);             // guard rcp rounding
            if (dd == 0.0f) dd = 1.0f;                      // jnp.where(d==0,1,d)
            d[k] = dd;
        }
        // exclusive products via prefix/suffix (no divides)
        float pre[RW], suf[RW];
        pre[0] = 1.0f;
        #pragma unroll
        for (int k = 1; k < RW; ++k) pre[k] = pre[k-1] * d[k-1];
        suf[RW-1] = 1.0f;
        #pragma unroll
        for (int k = RW-2; k >= 0; --k) suf[k] = suf[k+1] * d[k+1];

        #pragma unroll
        for (int k = 0; k < RW; ++k) {
            float x  = pre[k] * suf[k];
            float r  = (1.0f + x) * __builtin_amdgcn_rcpf(1.0f - x);
            float nm = sgn * __logf(r) + rw_ * msg[k];      // 2*atanh(x)*sgn + res*msg
            msg[k] = nm;
            atomicAdd(&s_S[ns][col[k]], nm * wS[k]);        // next layer's var-node sum
            atomicAdd(&s_bel[bb][col[k]], nm * marg[k]);    // beliefs
        }

        // rotate prefetched weights
        #pragma unroll
        for (int k = 0; k < RW; ++k) { bc[k] = bn[k]; wS[k] = wn2[k]; }

        __syncthreads();   // the ONE barrier per layer
    }

    // tail: loss for the last layer
    {
        const float rr = s_rho[LL - 1];
        const int   pb = (LL - 1) & 1;
        float acc = 0.0f;
        #pragma unroll
        for (int i = 0; i < 4; ++i) {
            int n = t + i * 384;
            float be = s_bel[pb][n];
            float sp = fmaxf(be, 0.0f) + __logf(1.0f + __expf(-fabsf(be)));
            acc += sp - omeg[i] * be;
        }
        loss += rr * acc;
    }

    // ---- block-wide loss reduction ----
    #pragma unroll
    for (int off = 32; off > 0; off >>= 1)
        loss += __shfl_down(loss, off, 64);
    int wave = t >> 6, lane = t & 63;
    if (lane == 0) s_red[wave] = loss;
    __syncthreads();
    if (t == 0) {
        float tot = 0.0f;
        #pragma unroll
        for (int w = 0; w < 6; ++w) tot += s_red[w];
        atomicAdd(out, tot * (1.0f / (float)MB));
    }
}

// ---------------------------------------------------------------------------
extern "C" void kernel_launch(void* const* d_in, const int* in_sizes, int n_in,
                              void* d_out, int out_size, void* d_ws, size_t ws_size,
                              hipStream_t stream) {
    const float* synd     = (const float*)d_in[0];  // (B,M,1)
    const float* errors   = (const float*)d_in[1];  // (B,N)
    const float* H        = (const float*)d_in[2];  // (M,N)
    const float* llrs     = (const float*)d_in[3];  // (N)
    const float* w_de     = (const float*)d_in[4];  // (L,M,N)
    const float* w_llr    = (const float*)d_in[5];  // (L,N)
    const float* marg_de  = (const float*)d_in[6];  // (M,N)
    const float* marg_llr = (const float*)d_in[7];  // (N)
    const float* res_w    = (const float*)d_in[8];  // (L)
    const float* rhos     = (const float*)d_in[9];  // (L)
    float* out = (float*)d_out;

    // Workspace layout (4-byte elements, 16B-aligned partitions)
    int*   col_idx = (int*)d_ws;            // NE ints
    float* marg_e  = (float*)d_ws + NE;     // NE floats
    float* base_e  = marg_e + NE;           // L*NE floats
    float* wde_e   = base_e + LL * NE;      // L*NE floats

    setup_kernel<<<MM, 256, 0, stream>>>(H, llrs, w_llr, w_de, marg_de,
                                         col_idx, marg_e, base_e, wde_e, out);
    bp_kernel<<<MB, 384, 0, stream>>>(synd, errors, llrs, marg_llr, res_w, rhos,
                                      col_idx, marg_e, base_e, wde_e, out);
}